// Round 3
// baseline (1173.121 us; speedup 1.0000x reference)
//
#include <hip/hip_runtime.h>
#include <math.h>

// Problem: B=2, T=2048, C=1024, H=16, D=64.
// Input/output dtype is sniffed at runtime (f32 vs bf16) — see detect_k.
#define Bdim 2
#define Tdim 2048
#define Cdim 1024
#define Hdim 16
#define Ddim 64

typedef unsigned short u16;
typedef __attribute__((ext_vector_type(8))) short bf16x8;  // 8 bf16 = 4 VGPRs
typedef __attribute__((ext_vector_type(4))) float f32x4;

__device__ __forceinline__ float b2f(u16 s){
  union { float f; unsigned u; } v; v.u = ((unsigned)s) << 16; return v.f;
}
__device__ __forceinline__ u16 f2b(float f){
  union { float f; unsigned u; } v; v.f = f;
  unsigned r = v.u + 0x7fffu + ((v.u >> 16) & 1u);  // RNE
  return (u16)(r >> 16);
}
// flag-dispatched scalar load of an INPUT tensor element (bf=1: bf16, bf=0: f32)
__device__ __forceinline__ float loadf(const void* p, size_t i, int bf){
  float r;
  if(bf) r = b2f(((const u16*)p)[i]);
  else   r = ((const float*)p)[i];
  return r;
}
__device__ __forceinline__ f32x4 mfma16(bf16x8 a, bf16x8 b, f32x4 c){
  return __builtin_amdgcn_mfma_f32_16x16x32_bf16(a, b, c, 0, 0, 0);
}

// ---------------- dtype sniffer -------------------------------------------
// bf16 data: every u16 is a sane bf16 (exp field in [0x6E,0x8A] or 0) for
// N(0,1) x. f32 data: high halves sane, low halves (mantissa bits) ~12% sane.
// Expected sane/64: bf16 ~64, f32 ~36. Threshold 56.
__global__ void detect_k(const u16* __restrict__ x, int* __restrict__ flag){
  if(threadIdx.x == 0 && blockIdx.x == 0){
    int sane = 0;
    for(int i = 0; i < 64; i++){
      int e = (x[i] >> 7) & 0xFF;
      sane += (e == 0 || (e >= 0x6E && e <= 0x8A)) ? 1 : 0;
    }
    *flag = (sane >= 56) ? 1 : 0;
  }
}

// ---------------- input convert (enc_hat -> bf16) -------------------------
__global__ __launch_bounds__(256) void cvt_k(const void* __restrict__ in,
    u16* __restrict__ out, int n, const int* __restrict__ flagp){
  int bf = *flagp;
  int i = blockIdx.x * 256 + threadIdx.x;
  if(i < n) out[i] = bf ? ((const u16*)in)[i] : f2b(((const float*)in)[i]);
}

// ---------------- weight transpose: in[K][N] -> out[N][K] (bf16) ----------
__global__ __launch_bounds__(256) void transpose_k(const void* __restrict__ in,
    u16* __restrict__ out, int K, int N, const int* __restrict__ flagp){
  __shared__ u16 tile[32][34];
  int bf = *flagp;
  int n0 = blockIdx.x * 32, k0 = blockIdx.y * 32;
  int tx = threadIdx.x & 31, ty = threadIdx.x >> 5;  // 32 x 8
  for(int i = 0; i < 4; i++)
    tile[ty + i*8][tx] = f2b(loadf(in, (size_t)(k0 + ty + i*8) * N + n0 + tx, bf));
  __syncthreads();
  for(int i = 0; i < 4; i++)
    out[(size_t)(n0 + ty + i*8) * K + k0 + tx] = tile[tx][ty + i*8];
}

// ---------------- LayerNorm over C=1024, one block per row ----------------
// SRC=0: x is the INPUT tensor (flag dtype). SRC=1: x is internal f32.
template<int SRC>
__global__ __launch_bounds__(256) void ln_k(const void* __restrict__ xin,
    const void* __restrict__ g, const void* __restrict__ be,
    u16* __restrict__ out, const int* __restrict__ flagp){
  __shared__ float red[256];
  int bf = *flagp;
  int row = blockIdx.x, t = threadIdx.x;
  float v[4]; float s = 0.f;
  for(int i = 0; i < 4; i++){
    size_t idx = (size_t)row * Cdim + t + i*256;
    v[i] = (SRC == 1) ? ((const float*)xin)[idx] : loadf(xin, idx, bf);
    s += v[i];
  }
  red[t] = s; __syncthreads();
  for(int o = 128; o > 0; o >>= 1){ if(t < o) red[t] += red[t+o]; __syncthreads(); }
  float mu = red[0] * (1.f / Cdim);
  __syncthreads();
  s = 0.f;
  for(int i = 0; i < 4; i++){ float d = v[i] - mu; s += d*d; }
  red[t] = s; __syncthreads();
  for(int o = 128; o > 0; o >>= 1){ if(t < o) red[t] += red[t+o]; __syncthreads(); }
  float rstd = rsqrtf(red[0] * (1.f / Cdim) + 1e-5f);
  u16* orow = out + (size_t)row * Cdim;
  for(int i = 0; i < 4; i++){
    int c = t + i*256;
    orow[c] = f2b((v[i] - mu) * rstd * loadf(g, c, bf) + loadf(be, c, bf));
  }
}

// ---------------- generic MFMA GEMM: C = A(MxK) * Bt(NxK)^T + bias --------
// A and Bt are ALWAYS internal bf16. bias / res-x / final-out flex on flag.
enum { EPI_QKV = 0, EPI_RES = 1, EPI_GELU = 2, EPI_FINAL = 3 };

template<int EPI>
__global__ __launch_bounds__(256) void gemm_k(
    const u16* __restrict__ A, const u16* __restrict__ Bt, const void* __restrict__ bias,
    void* __restrict__ out0, void* __restrict__ out1, const void* __restrict__ res,
    int M, int N, int K, int mofs, const int* __restrict__ flagp)
{
  __shared__ u16 As[64][40];   // row stride 80 B (multiple of 16): aligned b128
  __shared__ u16 Bs[64][40];
  int bf = *flagp;
  int tid = threadIdx.x;
  int m0 = blockIdx.y * 64, n0 = blockIdx.x * 64;
  int w = tid >> 6, l = tid & 63;
  int lq = l & 15, lk = l >> 4;
  int srow = tid >> 2, scol = (tid & 3) * 8;   // staging: 1x16B per thread
  int m_off = (w & 1) * 32, n_off = (w >> 1) * 32;
  f32x4 acc[2][2] = {};
  int bn = n0 + srow;
  if(EPI == EPI_QKV && bn >= 1024) bn += 1024;  // skip unused K-projection cols
  const u16* aptr = A  + (size_t)(m0 + srow) * K + scol;
  const u16* bptr = Bt + (size_t)bn * K + scol;
  for(int k0 = 0; k0 < K; k0 += 32){
    *(bf16x8*)&As[srow][scol] = *(const bf16x8*)(aptr + k0);
    *(bf16x8*)&Bs[srow][scol] = *(const bf16x8*)(bptr + k0);
    __syncthreads();
    bf16x8 af[2], bfr[2];
    for(int mb = 0; mb < 2; mb++) af[mb]  = *(const bf16x8*)&As[m_off + mb*16 + lq][lk*8];
    for(int nb = 0; nb < 2; nb++) bfr[nb] = *(const bf16x8*)&Bs[n_off + nb*16 + lq][lk*8];
    for(int mb = 0; mb < 2; mb++)
      for(int nb = 0; nb < 2; nb++)
        acc[mb][nb] = mfma16(af[mb], bfr[nb], acc[mb][nb]);
    __syncthreads();
  }
  // epilogue: C/D layout row=(l>>4)*4+r, col=l&15
  for(int mb = 0; mb < 2; mb++) for(int nb = 0; nb < 2; nb++){
    for(int r = 0; r < 4; r++){
      int m = m0 + m_off + mb*16 + lk*4 + r;
      int n = n0 + n_off + nb*16 + lq;
      float v = acc[mb][nb][r];
      if(EPI == EPI_QKV){
        int bsrc = (n < 1024) ? n : n + 1024;
        v += loadf(bias, bsrc, bf);
        int bb = m / Tdim, t = m % Tdim;
        if(n < 1024){  // Q -> (B,H,T,D)
          int h = n >> 6, d = n & 63;
          ((u16*)out0)[(((size_t)(bb*Hdim + h)*Tdim + t) << 6) + d] = f2b(v);
        } else {       // V -> transposed (B,H,D,T) for PV B-fragments
          int nv = n - 1024; int h = nv >> 6, d = nv & 63;
          ((u16*)out1)[((size_t)(bb*Hdim + h)*Ddim + d)*Tdim + t] = f2b(v);
        }
      } else if(EPI == EPI_RES){        // x2(f32) = x(INPUT) + A@W + bias
        v += loadf(bias, n, bf) + loadf(res, (size_t)m*N + n, bf);
        ((float*)out0)[(size_t)m*N + n] = v;
      } else if(EPI == EPI_GELU){       // exact gelu -> bf16
        v += loadf(bias, n, bf);
        float gl = 0.5f * v * (1.0f + erff(v * 0.70710678118f));
        ((u16*)out0)[(size_t)m*N + n] = f2b(gl);
      } else {                          // final: x2(f32) + A@W + bias -> OUT
        v += loadf(bias, n, bf) + ((const float*)res)[(size_t)m*N + n];
        size_t oi = (size_t)(mofs + m) * N + n;
        if(bf) ((u16*)out0)[oi] = f2b(v);
        else   ((float*)out0)[oi] = v;
      }
    }
  }
}

// ---------------- fused LIF attention, flash-style ------------------------
// One block per (b, h, 64-row q-tile). 4 waves; wave w owns q rows [w*16,w*16+16).
// S=Q*E^T via MFMA; I=g*S+bias; r=lif(I); p=exp(r/8). rate<500 strictly so
// p <= e^62.5 ~ 1.4e27: finite, no max-subtraction needed. den >= 1 (diagonal).
__global__ __launch_bounds__(256) void attn_k(
    const u16* __restrict__ Q, const u16* __restrict__ Vt, const u16* __restrict__ E,
    const void* __restrict__ gain, const void* __restrict__ battn,
    u16* __restrict__ aout, const int* __restrict__ flagp)
{
  __shared__ u16 P[64][72];  // row stride 144 B (multiple of 16)
  int bf = *flagp;
  int qt = blockIdx.x & 31, bh = blockIdx.x >> 5;
  int b = bh >> 4, h = bh & 15;
  int tid = threadIdx.x, w = tid >> 6, l = tid & 63;
  int lq = l & 15, lk = l >> 4;
  const u16* Qb = Q  + (size_t)bh * Tdim * Ddim;
  const u16* Vb = Vt + (size_t)bh * Ddim * Tdim;
  const u16* Eh = E  + (size_t)h  * Tdim * Ddim;
  int qrow = qt * 64 + w * 16;
  bf16x8 qf[2];
  for(int ks = 0; ks < 2; ks++)
    qf[ks] = *(const bf16x8*)(Qb + (size_t)(qrow + lq) * Ddim + ks*32 + lk*8);
  float g4[4], b4[4];
  for(int r = 0; r < 4; r++){
    int t = qrow + lk*4 + r;
    g4[r] = loadf(gain, h * Tdim + t, bf);
    b4[r] = loadf(battn, h * Tdim + t, bf);
  }
  f32x4 num[4] = {};
  float den[4] = {0.f, 0.f, 0.f, 0.f};
  for(int st = 0; st <= qt; st++){
    f32x4 sc[4] = {};
    for(int ks = 0; ks < 2; ks++){
      for(int nb = 0; nb < 4; nb++){
        bf16x8 ef = *(const bf16x8*)(Eh + (size_t)(st*64 + nb*16 + lq) * Ddim + ks*32 + lk*8);
        sc[nb] = mfma16(qf[ks], ef, sc[nb]);
      }
    }
    float dsum[4] = {0.f, 0.f, 0.f, 0.f};
    for(int nb = 0; nb < 4; nb++){
      for(int r = 0; r < 4; r++){
        int sg = st*64 + nb*16 + lq;
        int qg = qrow + lk*4 + r;
        float I = g4[r] * sc[nb][r] + b4[r];
        float rate = 0.f;
        if(I > 1.0f + 1e-7f) rate = 1.0f / (0.002f - 0.02f * log1pf(-1.0f / I));
        float p = (sg <= qg) ? __expf(0.125f * rate) : 0.f;
        P[w*16 + lk*4 + r][nb*16 + lq] = f2b(p);
        dsum[r] += p;
      }
    }
    for(int o = 1; o < 16; o <<= 1)
      for(int r = 0; r < 4; r++) dsum[r] += __shfl_xor(dsum[r], o, 64);
    for(int r = 0; r < 4; r++) den[r] += dsum[r];
    __syncthreads();
    for(int ks = 0; ks < 2; ks++){
      bf16x8 pf = *(const bf16x8*)&P[w*16 + lq][ks*32 + lk*8];
      for(int nb = 0; nb < 4; nb++){
        bf16x8 vf = *(const bf16x8*)(Vb + (size_t)(nb*16 + lq) * Tdim + st*64 + ks*32 + lk*8);
        num[nb] = mfma16(pf, vf, num[nb]);
      }
    }
    __syncthreads();
  }
  for(int nb = 0; nb < 4; nb++){
    for(int r = 0; r < 4; r++){
      int t = qrow + lk*4 + r;
      int d = nb*16 + lq;
      float o = num[nb][r] / den[r];
      aout[((size_t)b * Tdim + t) * Cdim + h * Ddim + d] = f2b(o);
    }
  }
}

// --------------------------------------------------------------------------
// Arena (52.25 MB peak, lifetime reuse):
//   flag [0,256)
//   R0  : xn -> attn_out -> Wt_mlp1          (8 MB)
//   R1  : Wt_qkv -> Wt_out -> Wt_mlp2        (8 MB)
//   x2  : f32 residual (live to end)         (16 MB)
//   R3a : Q -> hn                            (8 MB)
//   R3b : V^T -> gelu quarter-buffer         (8 MB)
//   Ebf : enc_hat as bf16                    (4 MB)
extern "C" void kernel_launch(void* const* d_in, const int* in_sizes, int n_in,
                              void* d_out, int out_size, void* d_ws, size_t ws_size,
                              hipStream_t stream)
{
  const void* x      = d_in[0];
  const void* ln1_g  = d_in[1];
  const void* ln1_b  = d_in[2];
  const void* qkv_w  = d_in[3];
  const void* qkv_b  = d_in[4];
  const void* out_w  = d_in[5];
  const void* out_b  = d_in[6];
  const void* ln2_g  = d_in[7];
  const void* ln2_b  = d_in[8];
  const void* mlp_w1 = d_in[9];
  const void* mlp_b1 = d_in[10];
  const void* mlp_w2 = d_in[11];
  const void* mlp_b2 = d_in[12];
  const void* enc    = d_in[13];
  const void* gain   = d_in[14];
  const void* battn  = d_in[15];
  (void)in_sizes; (void)n_in; (void)out_size; (void)ws_size;

  const size_t MB = 1024 * 1024;
  char* ws = (char*)d_ws;
  int*   flag = (int*)(ws);
  u16*   R0   = (u16*)(ws + 256);
  u16*   R1   = (u16*)(ws + 256 + 8*MB);
  float* x2   = (float*)(ws + 256 + 16*MB);
  u16*   R3a  = (u16*)(ws + 256 + 32*MB);
  u16*   R3b  = (u16*)(ws + 256 + 40*MB);
  u16*   Ebf  = (u16*)(ws + 256 + 48*MB);

  dim3 blk(256);
  detect_k<<<1, 64, 0, stream>>>((const u16*)x, flag);
  // LN1 -> xn (R0)
  ln_k<0><<<4096, blk, 0, stream>>>(x, ln1_g, ln1_b, R0, flag);
  // qkv_w^T -> R1 ; enc -> bf16
  transpose_k<<<dim3(3072/32, 1024/32), blk, 0, stream>>>(qkv_w, R1, 1024, 3072, flag);
  cvt_k<<<(Hdim*Tdim*Ddim)/256, blk, 0, stream>>>(enc, Ebf, Hdim*Tdim*Ddim, flag);
  // QKV gemm: Q -> R3a, V^T -> R3b
  gemm_k<EPI_QKV><<<dim3(2048/64, 4096/64), blk, 0, stream>>>(
      R0, R1, qkv_b, R3a, R3b, nullptr, 4096, 2048, 1024, 0, flag);
  // attention -> attn_out (R0; xn dead)
  attn_k<<<dim3(Bdim*Hdim*(Tdim/64)), blk, 0, stream>>>(R3a, R3b, Ebf, gain, battn, R0, flag);
  // out_w^T -> R1 (Wt_qkv dead)
  transpose_k<<<dim3(1024/32, 1024/32), blk, 0, stream>>>(out_w, R1, 1024, 1024, flag);
  // out-proj + residual(x) -> x2 (f32)
  gemm_k<EPI_RES><<<dim3(1024/64, 4096/64), blk, 0, stream>>>(
      R0, R1, out_b, x2, nullptr, x, 4096, 1024, 1024, 0, flag);
  // LN2 -> hn (R3a; Q dead)
  ln_k<1><<<4096, blk, 0, stream>>>(x2, ln2_g, ln2_b, R3a, flag);
  // mlp_w1^T -> R0 (attn_out dead), mlp_w2^T -> R1 (Wt_out dead)
  transpose_k<<<dim3(4096/32, 1024/32), blk, 0, stream>>>(mlp_w1, R0, 1024, 4096, flag);
  transpose_k<<<dim3(1024/32, 4096/32), blk, 0, stream>>>(mlp_w2, R1, 4096, 1024, flag);
  // MLP in 4 quarters of 1024 rows (gelu buffer in R3b; V^T dead)
  for(int q = 0; q < 4; q++){
    int ro = q * 1024;
    gemm_k<EPI_GELU><<<dim3(4096/64, 1024/64), blk, 0, stream>>>(
        R3a + (size_t)ro*1024, R0, mlp_b1, R3b, nullptr, nullptr, 1024, 4096, 1024, 0, flag);
    gemm_k<EPI_FINAL><<<dim3(1024/64, 1024/64), blk, 0, stream>>>(
        R3b, R1, mlp_b2, d_out, nullptr, x2 + (size_t)ro*1024, 1024, 1024, 4096, ro, flag);
  }
}

// Round 5
// 744.556 us; speedup vs baseline: 1.5756x; 1.5756x over previous
//
#include <hip/hip_runtime.h>
#include <math.h>

// Problem: B=2, T=2048, C=1024, H=16, D=64.
// Input/output dtype is sniffed at runtime (f32 vs bf16) — see detect_k.
#define Bdim 2
#define Tdim 2048
#define Cdim 1024
#define Hdim 16
#define Ddim 64

typedef unsigned short u16;
typedef __attribute__((ext_vector_type(8))) short bf16x8;  // 8 bf16 = 4 VGPRs
typedef __attribute__((ext_vector_type(4))) float f32x4;

__device__ __forceinline__ float b2f(u16 s){
  union { float f; unsigned u; } v; v.u = ((unsigned)s) << 16; return v.f;
}
__device__ __forceinline__ u16 f2b(float f){
  union { float f; unsigned u; } v; v.f = f;
  unsigned r = v.u + 0x7fffu + ((v.u >> 16) & 1u);  // RNE
  return (u16)(r >> 16);
}
// flag-dispatched scalar load of an INPUT tensor element (bf=1: bf16, bf=0: f32)
__device__ __forceinline__ float loadf(const void* p, size_t i, int bf){
  float r;
  if(bf) r = b2f(((const u16*)p)[i]);
  else   r = ((const float*)p)[i];
  return r;
}
__device__ __forceinline__ f32x4 mfma16(bf16x8 a, bf16x8 b, f32x4 c){
  return __builtin_amdgcn_mfma_f32_16x16x32_bf16(a, b, c, 0, 0, 0);
}

// ---------------- dtype sniffer -------------------------------------------
__global__ void detect_k(const u16* __restrict__ x, int* __restrict__ flag){
  if(threadIdx.x == 0 && blockIdx.x == 0){
    int sane = 0;
    for(int i = 0; i < 64; i++){
      int e = (x[i] >> 7) & 0xFF;
      sane += (e == 0 || (e >= 0x6E && e <= 0x8A)) ? 1 : 0;
    }
    *flag = (sane >= 56) ? 1 : 0;
  }
}

// ---------------- input convert (enc_hat -> bf16) -------------------------
__global__ __launch_bounds__(256) void cvt_k(const void* __restrict__ in,
    u16* __restrict__ out, int n, const int* __restrict__ flagp){
  int bf = *flagp;
  int i = blockIdx.x * 256 + threadIdx.x;
  if(i < n) out[i] = bf ? ((const u16*)in)[i] : f2b(((const float*)in)[i]);
}

// ---------------- weight transpose: in[K][N] -> out[N][K] (bf16) ----------
__global__ __launch_bounds__(256) void transpose_k(const void* __restrict__ in,
    u16* __restrict__ out, int K, int N, const int* __restrict__ flagp){
  __shared__ u16 tile[32][34];
  int bf = *flagp;
  int n0 = blockIdx.x * 32, k0 = blockIdx.y * 32;
  int tx = threadIdx.x & 31, ty = threadIdx.x >> 5;  // 32 x 8
  for(int i = 0; i < 4; i++)
    tile[ty + i*8][tx] = f2b(loadf(in, (size_t)(k0 + ty + i*8) * N + n0 + tx, bf));
  __syncthreads();
  for(int i = 0; i < 4; i++)
    out[(size_t)(n0 + ty + i*8) * K + k0 + tx] = tile[tx][ty + i*8];
}

// ---------------- LayerNorm over C=1024, one block per row ----------------
template<int SRC>
__global__ __launch_bounds__(256) void ln_k(const void* __restrict__ xin,
    const void* __restrict__ g, const void* __restrict__ be,
    u16* __restrict__ out, const int* __restrict__ flagp){
  __shared__ float red[256];
  int bf = *flagp;
  int row = blockIdx.x, t = threadIdx.x;
  float v[4]; float s = 0.f;
  for(int i = 0; i < 4; i++){
    size_t idx = (size_t)row * Cdim + t + i*256;
    v[i] = (SRC == 1) ? ((const float*)xin)[idx] : loadf(xin, idx, bf);
    s += v[i];
  }
  red[t] = s; __syncthreads();
  for(int o = 128; o > 0; o >>= 1){ if(t < o) red[t] += red[t+o]; __syncthreads(); }
  float mu = red[0] * (1.f / Cdim);
  __syncthreads();
  s = 0.f;
  for(int i = 0; i < 4; i++){ float d = v[i] - mu; s += d*d; }
  red[t] = s; __syncthreads();
  for(int o = 128; o > 0; o >>= 1){ if(t < o) red[t] += red[t+o]; __syncthreads(); }
  float rstd = rsqrtf(red[0] * (1.f / Cdim) + 1e-5f);
  u16* orow = out + (size_t)row * Cdim;
  for(int i = 0; i < 4; i++){
    int c = t + i*256;
    orow[c] = f2b((v[i] - mu) * rstd * loadf(g, c, bf) + loadf(be, c, bf));
  }
}

// ---------------- generic MFMA GEMM: C = A(MxK) * Bt(NxK)^T + bias --------
enum { EPI_QKV = 0, EPI_RES = 1, EPI_GELU = 2, EPI_FINAL = 3 };

template<int EPI>
__global__ __launch_bounds__(256) void gemm_k(
    const u16* __restrict__ A, const u16* __restrict__ Bt, const void* __restrict__ bias,
    void* __restrict__ out0, void* __restrict__ out1, const void* __restrict__ res,
    int M, int N, int K, int mofs, const int* __restrict__ flagp)
{
  __shared__ u16 As[64][40];   // row stride 80 B (multiple of 16): aligned b128
  __shared__ u16 Bs[64][40];
  int bf = *flagp;
  int tid = threadIdx.x;
  int m0 = blockIdx.y * 64, n0 = blockIdx.x * 64;
  int w = tid >> 6, l = tid & 63;
  int lq = l & 15, lk = l >> 4;
  int srow = tid >> 2, scol = (tid & 3) * 8;   // staging: 1x16B per thread
  int m_off = (w & 1) * 32, n_off = (w >> 1) * 32;
  f32x4 acc[2][2] = {};
  int bn = n0 + srow;
  if(EPI == EPI_QKV && bn >= 1024) bn += 1024;  // skip unused K-projection cols
  const u16* aptr = A  + (size_t)(m0 + srow) * K + scol;
  const u16* bptr = Bt + (size_t)bn * K + scol;
  for(int k0 = 0; k0 < K; k0 += 32){
    *(bf16x8*)&As[srow][scol] = *(const bf16x8*)(aptr + k0);
    *(bf16x8*)&Bs[srow][scol] = *(const bf16x8*)(bptr + k0);
    __syncthreads();
    bf16x8 af[2], bfr[2];
    for(int mb = 0; mb < 2; mb++) af[mb]  = *(const bf16x8*)&As[m_off + mb*16 + lq][lk*8];
    for(int nb = 0; nb < 2; nb++) bfr[nb] = *(const bf16x8*)&Bs[n_off + nb*16 + lq][lk*8];
    for(int mb = 0; mb < 2; mb++)
      for(int nb = 0; nb < 2; nb++)
        acc[mb][nb] = mfma16(af[mb], bfr[nb], acc[mb][nb]);
    __syncthreads();
  }
  // epilogue: C/D layout row=(l>>4)*4+r, col=l&15
  for(int mb = 0; mb < 2; mb++) for(int nb = 0; nb < 2; nb++){
    for(int r = 0; r < 4; r++){
      int m = m0 + m_off + mb*16 + lk*4 + r;
      int n = n0 + n_off + nb*16 + lq;
      float v = acc[mb][nb][r];
      if(EPI == EPI_QKV){
        int bsrc = (n < 1024) ? n : n + 1024;
        v += loadf(bias, bsrc, bf);
        int bb = m / Tdim, t = m % Tdim;
        if(n < 1024){  // Q -> (B,H,T,D)
          int h = n >> 6, d = n & 63;
          ((u16*)out0)[(((size_t)(bb*Hdim + h)*Tdim + t) << 6) + d] = f2b(v);
        } else {       // V -> transposed (B,H,D,T) for PV B-fragments
          int nv = n - 1024; int h = nv >> 6, d = nv & 63;
          ((u16*)out1)[((size_t)(bb*Hdim + h)*Ddim + d)*Tdim + t] = f2b(v);
        }
      } else if(EPI == EPI_RES){        // x2(f32) = x(INPUT) + A@W + bias
        v += loadf(bias, n, bf) + loadf(res, (size_t)m*N + n, bf);
        ((float*)out0)[(size_t)m*N + n] = v;
      } else if(EPI == EPI_GELU){       // exact gelu -> bf16
        v += loadf(bias, n, bf);
        float gl = 0.5f * v * (1.0f + erff(v * 0.70710678118f));
        ((u16*)out0)[(size_t)m*N + n] = f2b(gl);
      } else {                          // final: x2(f32) + A@W + bias -> OUT
        v += loadf(bias, n, bf) + ((const float*)res)[(size_t)m*N + n];
        size_t oi = (size_t)(mofs + m) * N + n;
        if(bf) ((u16*)out0)[oi] = f2b(v);
        else   ((float*)out0)[oi] = v;
      }
    }
  }
}

// ---------------- fused LIF attention, flash-style ------------------------
// One block per (b, h, 64-row q-tile). Wave w privately owns q-rows
// [w*16, w*16+16): P band is wave-private -> NO __syncthreads in the st loop.
// qt = blockIdx>>5 so co-resident blocks per CU carry different qt
// (fixes the mod-32 CU imbalance seen in round 3: all-same-qt per CU).
// LIF via hw transcendentals: rate = 1/(2e-3 + 2e-2*ln2*(log2 I - log2(I-1))),
// p = exp2(0.125*log2e*rate) <= e^62.5 (finite; no max-subtraction).
// Denominator via MFMA against a ones B-fragment (replaces shfl butterfly).
__global__ __launch_bounds__(256) void attn_k(
    const u16* __restrict__ Q, const u16* __restrict__ Vt, const u16* __restrict__ E,
    const void* __restrict__ gain, const void* __restrict__ battn,
    u16* __restrict__ aout, const int* __restrict__ flagp)
{
  __shared__ u16 P[64][72];  // row stride 144 B (multiple of 16)
  int bf = *flagp;
  int qt = blockIdx.x >> 5, bh = blockIdx.x & 31;
  int b = bh >> 4, h = bh & 15;
  int tid = threadIdx.x, w = tid >> 6, l = tid & 63;
  int lq = l & 15, lk = l >> 4;
  const u16* Qb = Q  + (size_t)bh * Tdim * Ddim;
  const u16* Vb = Vt + (size_t)bh * Ddim * Tdim;
  const u16* Eh = E  + (size_t)h  * Tdim * Ddim;
  int qrow = qt * 64 + w * 16;
  bf16x8 qf[2];
  for(int ks = 0; ks < 2; ks++)
    qf[ks] = *(const bf16x8*)(Qb + (size_t)(qrow + lq) * Ddim + ks*32 + lk*8);
  float g4[4], b4[4];
  for(int r = 0; r < 4; r++){
    int t = qrow + lk*4 + r;
    g4[r] = loadf(gain, h * Tdim + t, bf);
    b4[r] = loadf(battn, h * Tdim + t, bf);
  }
  bf16x8 onesf;
  for(int j = 0; j < 8; j++) onesf[j] = (short)0x3F80;  // bf16 1.0
  f32x4 num[4] = {};
  f32x4 den4 = {0.f, 0.f, 0.f, 0.f};
  for(int st = 0; st <= qt; st++){
    f32x4 sc[4] = {};
    for(int ks = 0; ks < 2; ks++){
      for(int nb = 0; nb < 4; nb++){
        bf16x8 ef = *(const bf16x8*)(Eh + (size_t)(st*64 + nb*16 + lq) * Ddim + ks*32 + lk*8);
        sc[nb] = mfma16(qf[ks], ef, sc[nb]);
      }
    }
    for(int nb = 0; nb < 4; nb++){
      for(int r = 0; r < 4; r++){
        int sg = st*64 + nb*16 + lq;
        int qg = qrow + lk*4 + r;
        float I = fmaf(g4[r], sc[nb][r], b4[r]);
        // LIF rate via hw log2/rcp (v_log_f32/v_exp_f32); NaN (I<1) killed by select
        float L = __builtin_amdgcn_logf(I) - __builtin_amdgcn_logf(I - 1.0f);
        float denom = fmaf(0.013862944f, L, 0.002f);
        float e = __builtin_amdgcn_exp2f(0.18033688f * __builtin_amdgcn_rcpf(denom));
        float p = (I > 1.0000001f) ? e : 1.0f;
        p = (sg <= qg) ? p : 0.f;
        P[w*16 + lk*4 + r][nb*16 + lq] = f2b(p);
      }
    }
    // wave-private LDS band: compiler inserts lgkmcnt wait, no barrier needed
    for(int ks = 0; ks < 2; ks++){
      bf16x8 pf = *(const bf16x8*)&P[w*16 + lq][ks*32 + lk*8];
      den4 = mfma16(pf, onesf, den4);   // rowsum -> denominator (C-layout rows)
      for(int nb = 0; nb < 4; nb++){
        bf16x8 vf = *(const bf16x8*)(Vb + (size_t)(nb*16 + lq) * Tdim + st*64 + ks*32 + lk*8);
        num[nb] = mfma16(pf, vf, num[nb]);
      }
    }
  }
  float rden[4];
  for(int r = 0; r < 4; r++) rden[r] = __builtin_amdgcn_rcpf(den4[r]);
  for(int nb = 0; nb < 4; nb++){
    for(int r = 0; r < 4; r++){
      int t = qrow + lk*4 + r;
      int d = nb*16 + lq;
      float o = num[nb][r] * rden[r];
      aout[((size_t)b * Tdim + t) * Cdim + h * Ddim + d] = f2b(o);
    }
  }
}

// --------------------------------------------------------------------------
// Arena (52.25 MB peak, lifetime reuse) — validated in round 3.
extern "C" void kernel_launch(void* const* d_in, const int* in_sizes, int n_in,
                              void* d_out, int out_size, void* d_ws, size_t ws_size,
                              hipStream_t stream)
{
  const void* x      = d_in[0];
  const void* ln1_g  = d_in[1];
  const void* ln1_b  = d_in[2];
  const void* qkv_w  = d_in[3];
  const void* qkv_b  = d_in[4];
  const void* out_w  = d_in[5];
  const void* out_b  = d_in[6];
  const void* ln2_g  = d_in[7];
  const void* ln2_b  = d_in[8];
  const void* mlp_w1 = d_in[9];
  const void* mlp_b1 = d_in[10];
  const void* mlp_w2 = d_in[11];
  const void* mlp_b2 = d_in[12];
  const void* enc    = d_in[13];
  const void* gain   = d_in[14];
  const void* battn  = d_in[15];
  (void)in_sizes; (void)n_in; (void)out_size; (void)ws_size;

  const size_t MB = 1024 * 1024;
  char* ws = (char*)d_ws;
  int*   flag = (int*)(ws);
  u16*   R0   = (u16*)(ws + 256);
  u16*   R1   = (u16*)(ws + 256 + 8*MB);
  float* x2   = (float*)(ws + 256 + 16*MB);
  u16*   R3a  = (u16*)(ws + 256 + 32*MB);
  u16*   R3b  = (u16*)(ws + 256 + 40*MB);
  u16*   Ebf  = (u16*)(ws + 256 + 48*MB);

  dim3 blk(256);
  detect_k<<<1, 64, 0, stream>>>((const u16*)x, flag);
  ln_k<0><<<4096, blk, 0, stream>>>(x, ln1_g, ln1_b, R0, flag);
  transpose_k<<<dim3(3072/32, 1024/32), blk, 0, stream>>>(qkv_w, R1, 1024, 3072, flag);
  cvt_k<<<(Hdim*Tdim*Ddim)/256, blk, 0, stream>>>(enc, Ebf, Hdim*Tdim*Ddim, flag);
  gemm_k<EPI_QKV><<<dim3(2048/64, 4096/64), blk, 0, stream>>>(
      R0, R1, qkv_b, R3a, R3b, nullptr, 4096, 2048, 1024, 0, flag);
  attn_k<<<dim3(Bdim*Hdim*(Tdim/64)), blk, 0, stream>>>(R3a, R3b, Ebf, gain, battn, R0, flag);
  transpose_k<<<dim3(1024/32, 1024/32), blk, 0, stream>>>(out_w, R1, 1024, 1024, flag);
  gemm_k<EPI_RES><<<dim3(1024/64, 4096/64), blk, 0, stream>>>(
      R0, R1, out_b, x2, nullptr, x, 4096, 1024, 1024, 0, flag);
  ln_k<1><<<4096, blk, 0, stream>>>(x2, ln2_g, ln2_b, R3a, flag);
  transpose_k<<<dim3(4096/32, 1024/32), blk, 0, stream>>>(mlp_w1, R0, 1024, 4096, flag);
  transpose_k<<<dim3(1024/32, 4096/32), blk, 0, stream>>>(mlp_w2, R1, 4096, 1024, flag);
  for(int q = 0; q < 4; q++){
    int ro = q * 1024;
    gemm_k<EPI_GELU><<<dim3(4096/64, 1024/64), blk, 0, stream>>>(
        R3a + (size_t)ro*1024, R0, mlp_b1, R3b, nullptr, nullptr, 1024, 4096, 1024, 0, flag);
    gemm_k<EPI_FINAL><<<dim3(1024/64, 1024/64), blk, 0, stream>>>(
        R3b, R1, mlp_b2, d_out, nullptr, x2 + (size_t)ro*1024, 1024, 1024, 4096, ro, flag);
  }
}